// Round 8
// baseline (867.465 us; speedup 1.0000x reference)
//
#include <hip/hip_runtime.h>
#include <hip/hip_fp16.h>
#include <hip/hip_cooperative_groups.h>
#include <cstdint>
#include <cstddef>

#define NN 100000
#define EE 400000
#define CC 16
#define LL 16
#define NB 8        // stats atomic buckets
#define CAP 1024    // LDS m-slots per block
#define CSTR 1032   // padded LDS stride (1032%32==8 -> <=2-way conflicts)

namespace cg = cooperative_groups;
typedef unsigned int uint;

// ---------- device helpers ----------
__device__ __forceinline__ float lrelu(float v){ return v > 0.0f ? v : 0.01f*v; }

__device__ __forceinline__ float waveSum(float v){
#pragma unroll
  for (int off = 32; off >= 1; off >>= 1) v += __shfl_xor(v, off);
  return v;
}

__device__ __forceinline__ float fma4(float4 w, float4 v, float a){
  a = fmaf(w.x, v.x, a); a = fmaf(w.y, v.y, a);
  a = fmaf(w.z, v.z, a); a = fmaf(w.w, v.w, a);
  return a;
}

__device__ __forceinline__ uint pack_h2(float a, float b){
  __half2 h = __floats2half2_rn(a, b);
  return *reinterpret_cast<uint*>(&h);
}
__device__ __forceinline__ float2 unpack_h2(uint v){
  __half2 h = *reinterpret_cast<__half2*>(&v);
  return __half22float2(h);
}

// ---------- init: count degrees (int atomics only) ----------
__global__ __launch_bounds__(256) void k_count(const int* __restrict__ ei,
    int* __restrict__ cdst, int* __restrict__ call)
{
  int t = blockIdx.x*256 + threadIdx.x;
  if (t >= EE) return;
  int s = ei[t], d = ei[EE + t];
  atomicAdd(&cdst[d], 1);
  atomicAdd(&call[s], 1);
  atomicAdd(&call[d], 1);
}

// ---------- dual exclusive scan (SEG=1024/block) ----------
__device__ __forceinline__ void scan_one(const int* __restrict__ cnt,
    int* __restrict__ rp, int* __restrict__ bsums, int n, int* sd)
{
  int tid = threadIdx.x;
  int base = blockIdx.x*1024 + tid*4;
  int v0=0,v1=0,v2=0,v3=0;
  if (base+0 < n) v0 = cnt[base+0];
  if (base+1 < n) v1 = cnt[base+1];
  if (base+2 < n) v2 = cnt[base+2];
  if (base+3 < n) v3 = cnt[base+3];
  int tot = v0+v1+v2+v3;
  sd[tid] = tot; __syncthreads();
  for (int off=1; off<256; off<<=1){
    int add = (tid>=off) ? sd[tid-off] : 0;
    __syncthreads();
    sd[tid] += add;
    __syncthreads();
  }
  int excl = sd[tid] - tot;
  if (base+0 < n) rp[base+0] = excl;
  if (base+1 < n) rp[base+1] = excl+v0;
  if (base+2 < n) rp[base+2] = excl+v0+v1;
  if (base+3 < n) rp[base+3] = excl+v0+v1+v2;
  if (tid==255) bsums[blockIdx.x] = sd[255];
  __syncthreads();
}

__global__ __launch_bounds__(256) void k_scan1(const int* __restrict__ ca,
    int* __restrict__ rpa, int* __restrict__ bsa,
    const int* __restrict__ cb, int* __restrict__ rpb, int* __restrict__ bsb, int n)
{
  __shared__ int sd[256];
  scan_one(ca, rpa, bsa, n, sd);
  scan_one(cb, rpb, bsb, n, sd);
}

__device__ __forceinline__ void scan2_one(const int* __restrict__ bsums,
    int* __restrict__ boff, int nseg, int* sd)
{
  int tid = threadIdx.x;
  int v = (tid < nseg) ? bsums[tid] : 0;
  sd[tid] = v; __syncthreads();
  for (int off=1; off<256; off<<=1){
    int add = (tid>=off) ? sd[tid-off] : 0;
    __syncthreads();
    sd[tid] += add;
    __syncthreads();
  }
  if (tid < nseg) boff[tid] = sd[tid] - v;
  __syncthreads();
}

__global__ __launch_bounds__(256) void k_scan2(const int* __restrict__ bsa,
    int* __restrict__ boffa, const int* __restrict__ bsb, int* __restrict__ boffb, int nseg)
{
  __shared__ int sd[256];
  scan2_one(bsa, boffa, nseg, sd);
  scan2_one(bsb, boffb, nseg, sd);
}

__global__ __launch_bounds__(256) void k_scan3(
    int* __restrict__ rpa, int* __restrict__ cura, const int* __restrict__ boffa, int totala,
    int* __restrict__ rpb, int* __restrict__ curb, const int* __restrict__ boffb, int totalb, int n)
{
  int adda = boffa[blockIdx.x];
  int addb = boffb[blockIdx.x];
  int base = blockIdx.x*1024 + threadIdx.x*4;
#pragma unroll
  for (int i=0;i<4;i++){
    if (base+i < n){
      int va = rpa[base+i] + adda; rpa[base+i] = va; cura[base+i] = va;
      int vb = rpb[base+i] + addb; rpb[base+i] = vb; curb[base+i] = vb;
    }
  }
  if (blockIdx.x==0 && threadIdx.x==0){ rpa[n] = totala; rpb[n] = totalb; }
}

// ---------- fill: dst-sorted (src,dst) pairs + all-CSR edge list ----------
__global__ __launch_bounds__(256) void k_fill(const int* __restrict__ ei,
    int* __restrict__ cur, int2* __restrict__ sd,
    int* __restrict__ cur_all, int* __restrict__ list_all)
{
  int t = blockIdx.x*256 + threadIdx.x;
  if (t >= EE) return;
  int s = ei[t], d = ei[EE + t];
  int p = atomicAdd(&cur[d], 1);
  sd[p] = make_int2(s, d);
  int pa = atomicAdd(&cur_all[s], 1);
  list_all[pa] = t;
  int pb = atomicAdd(&cur_all[d], 1);
  list_all[pb] = t;
}

// ---------- x0 = mean of incident edge features; invdeg = 1/clip(deg_in,1) ----------
__global__ __launch_bounds__(256) void k_gather0(const float* __restrict__ ef,
    const int* __restrict__ rp_all, const int* __restrict__ list_all,
    const int* __restrict__ rp, float* __restrict__ x0, float* __restrict__ invdeg)
{
  int t = blockIdx.x*256 + threadIdx.x;
  if (t >= NN*CC) return;
  int n = t >> 4, c = t & 15;
  int beg = rp_all[n], end = rp_all[n+1];
  float acc = 0.0f;
  for (int i=beg; i<end; i++){
    acc += ef[(size_t)list_all[i]*CC + c];
  }
  float dg = fmaxf((float)(end-beg), 1.0f);
  x0[t] = acc / dg;
  if (c == 0){
    int di = rp[n+1] - rp[n];
    invdeg[n] = 1.0f / fmaxf((float)di, 1.0f);
  }
}

// ---------- persistent cooperative kernel: 16 layers + final BN/output ----------
__global__ __launch_bounds__(256) void k_layers(
    float* __restrict__ xa, float* __restrict__ xb,
    const int2* __restrict__ sd, const int* __restrict__ rp,
    const float* __restrict__ invdeg, const int* __restrict__ ei,
    const float* __restrict__ Wn, const float* __restrict__ bn,
    const float* __restrict__ gn, const float* __restrict__ btn,
    const float* __restrict__ We, const float* __restrict__ be,
    const float* __restrict__ ge, const float* __restrict__ bte,
    double* __restrict__ stats, double* __restrict__ lossd,
    uint* __restrict__ mspill, float* __restrict__ out)
{
  cg::grid_group grid = cg::this_grid();
  __shared__ float sW[512];
  __shared__ float sb[16];
  __shared__ float sAB[32];
  __shared__ float sredS[64], sredQ[64];
  __shared__ float sl[4];
  __shared__ uint  sM[8*CSTR];   // fp16x2 m-tile: [chanpair][slot]

  const int tid = threadIdx.x;
  const int bid = blockIdx.x;
  const int nblk = gridDim.x;
  const int npb = (NN + nblk - 1) / nblk;
  int nlo = bid * npb; if (nlo > NN) nlo = NN;
  int nhi = nlo + npb; if (nhi > NN) nhi = NN;
  const int ebeg = rp[nlo];
  const int eend = rp[nhi];

  const float* xc = xa;
  float* xn = xb;

  float ls[16], lq[16];

  for (int l = 0; l < LL; ++l){
    const float* W = Wn + (size_t)l*512;
    for (int i = tid; i < 512; i += 256) sW[i] = W[i];
    if (tid < 16) sb[tid] = bn[l*16 + tid];
    __syncthreads();

#pragma unroll
    for (int c=0;c<16;c++){ ls[c]=0.f; lq[c]=0.f; }

    // ---- phase E: m for my edge segment -> LDS (fp16), stats in regs ----
    for (int i = ebeg + tid; i < eend; i += 256){
      int2 p = sd[i];
      const float4* xd4 = (const float4*)(xc + (size_t)p.y*CC);
      const float4* xs4 = (const float4*)(xc + (size_t)p.x*CC);
      float4 xd0=xd4[0], xd1=xd4[1], xd2=xd4[2], xd3=xd4[3];
      float4 xs0=xs4[0], xs1=xs4[1], xs2=xs4[2], xs3=xs4[3];
      int slot = i - ebeg;
      bool inl = slot < CAP;
      uint* gsp = mspill + (size_t)i*8;
#pragma unroll
      for (int q = 0; q < 8; ++q){
        const int c = 2*q;
        const float4* w0 = (const float4*)(sW + c*32);
        const float4* w1 = (const float4*)(sW + c*32 + 32);
        float a0 = sb[c], a1 = sb[c+1];
        a0 = fma4(w0[0],xd0,a0); a0 = fma4(w0[1],xd1,a0);
        a0 = fma4(w0[2],xd2,a0); a0 = fma4(w0[3],xd3,a0);
        a0 = fma4(w0[4],xs0,a0); a0 = fma4(w0[5],xs1,a0);
        a0 = fma4(w0[6],xs2,a0); a0 = fma4(w0[7],xs3,a0);
        a1 = fma4(w1[0],xd0,a1); a1 = fma4(w1[1],xd1,a1);
        a1 = fma4(w1[2],xd2,a1); a1 = fma4(w1[3],xd3,a1);
        a1 = fma4(w1[4],xs0,a1); a1 = fma4(w1[5],xs1,a1);
        a1 = fma4(w1[6],xs2,a1); a1 = fma4(w1[7],xs3,a1);
        ls[c]   += a0; lq[c]   += a0*a0;
        ls[c+1] += a1; lq[c+1] += a1*a1;
        uint pk = pack_h2(a0, a1);
        if (inl) sM[q*CSTR + slot] = pk; else gsp[q] = pk;
      }
    }

    // ---- block stats reduce -> bucketed f64 atomics ----
    {
      int lane = tid & 63, w = tid >> 6;
#pragma unroll
      for (int c=0;c<16;c++){
        float rs = waveSum(ls[c]);
        float rq = waveSum(lq[c]);
        if (lane==0){ sredS[w*16+c]=rs; sredQ[w*16+c]=rq; }
      }
      __syncthreads();
      double* stb = stats + (size_t)l*NB*32 + (size_t)(bid & (NB-1))*32;
      if (tid < 16){
        float tot = sredS[tid]+sredS[16+tid]+sredS[32+tid]+sredS[48+tid];
        unsafeAtomicAdd(&stb[tid], (double)tot);
      } else if (tid < 32){
        int c = tid-16;
        float tot = sredQ[c]+sredQ[16+c]+sredQ[32+c]+sredQ[48+c];
        unsafeAtomicAdd(&stb[16+c], (double)tot);
      }
    }
    __threadfence();
    grid.sync();

    // ---- A,B from global stats ----
    if (tid < 16){
      const double* stl = stats + (size_t)l*NB*32;
      double S=0.0, Q=0.0;
#pragma unroll
      for (int k=0;k<NB;k++){ S += stl[k*32+tid]; Q += stl[k*32+16+tid]; }
      double mu  = S * (1.0/EE);
      double var = Q * (1.0/EE) - mu*mu;
      float sc = rsqrtf((float)var + 1e-5f);
      float A = sc * gn[l*16+tid];
      sAB[tid] = A; sAB[16+tid] = btn[l*16+tid] - (float)mu * A;
    }
    __syncthreads();

    // ---- phase N: BN+leaky+segment-mean for my nodes (m from LDS) ----
    for (int u = tid; u < npb*8; u += 256){
      int n = nlo + (u>>3);
      if (n >= nhi) break;
      int cp = u & 7;
      float A0=sAB[2*cp],   B0=sAB[16+2*cp];
      float A1=sAB[2*cp+1], B1=sAB[16+2*cp+1];
      int beg = rp[n], end = rp[n+1];
      float a0=0.f, a1=0.f;
      for (int i=beg; i<end; ++i){
        int slot = i - ebeg;
        uint v = (slot < CAP) ? sM[cp*CSTR + slot] : mspill[(size_t)i*8 + cp];
        float2 f = unpack_h2(v);
        a0 += lrelu(fmaf(A0, f.x, B0));
        a1 += lrelu(fmaf(A1, f.y, B1));
      }
      float iv = invdeg[n];
      *(float2*)(xn + (size_t)n*CC + 2*cp) = make_float2(a0*iv, a1*iv);
    }
    __threadfence();
    grid.sync();
    const float* t = xc; xc = xn; xn = (float*)t;
  }

  // ================= final stage =================
  for (int i = tid; i < 512; i += 256) sW[i] = We[i];
  if (tid < 16) sb[tid] = be[tid];
  __syncthreads();

  const int epb = (EE + nblk - 1) / nblk;
  int fb = bid*epb; if (fb > EE) fb = EE;
  int fe = fb + epb; if (fe > EE) fe = EE;

#pragma unroll
  for (int c=0;c<16;c++){ ls[c]=0.f; lq[c]=0.f; }
  for (int t_ = fb + tid; t_ < fe; t_ += 256){
    int s = ei[t_], d = ei[EE+t_];
    const float4* ps = (const float4*)(xc + (size_t)s*CC);
    const float4* pd = (const float4*)(xc + (size_t)d*CC);
    float4 xs0=ps[0], xs1=ps[1], xs2=ps[2], xs3=ps[3];
    float4 xd0=pd[0], xd1=pd[1], xd2=pd[2], xd3=pd[3];
#pragma unroll
    for (int c=0;c<16;c++){
      const float4* wr = (const float4*)(sW + c*32);
      float f = sb[c], g_ = sb[c];
      f  = fma4(wr[0],xs0,f);  f  = fma4(wr[1],xs1,f);
      f  = fma4(wr[2],xs2,f);  f  = fma4(wr[3],xs3,f);
      f  = fma4(wr[4],xd0,f);  f  = fma4(wr[5],xd1,f);
      f  = fma4(wr[6],xd2,f);  f  = fma4(wr[7],xd3,f);
      g_ = fma4(wr[0],xd0,g_); g_ = fma4(wr[1],xd1,g_);
      g_ = fma4(wr[2],xd2,g_); g_ = fma4(wr[3],xd3,g_);
      g_ = fma4(wr[4],xs0,g_); g_ = fma4(wr[5],xs1,g_);
      g_ = fma4(wr[6],xs2,g_); g_ = fma4(wr[7],xs3,g_);
      ls[c] += f + g_;
      lq[c] += f*f + g_*g_;
    }
  }
  {
    int lane = tid & 63, w = tid >> 6;
#pragma unroll
    for (int c=0;c<16;c++){
      float rs = waveSum(ls[c]);
      float rq = waveSum(lq[c]);
      if (lane==0){ sredS[w*16+c]=rs; sredQ[w*16+c]=rq; }
    }
    __syncthreads();
    double* stb = stats + (size_t)LL*NB*32 + (size_t)(bid & (NB-1))*32;
    if (tid < 16){
      float tot = sredS[tid]+sredS[16+tid]+sredS[32+tid]+sredS[48+tid];
      unsafeAtomicAdd(&stb[tid], (double)tot);
    } else if (tid < 32){
      int c = tid-16;
      float tot = sredQ[c]+sredQ[16+c]+sredQ[32+c]+sredQ[48+c];
      unsafeAtomicAdd(&stb[16+c], (double)tot);
    }
  }
  __threadfence();
  grid.sync();

  if (tid < 16){
    const double* stl = stats + (size_t)LL*NB*32;
    double S=0.0, Q=0.0;
#pragma unroll
    for (int k=0;k<NB;k++){ S += stl[k*32+tid]; Q += stl[k*32+16+tid]; }
    double mu  = S * (1.0/(2.0*EE));
    double var = Q * (1.0/(2.0*EE)) - mu*mu;
    float sc = rsqrtf((float)var + 1e-5f);
    float A = sc * ge[tid];
    sAB[tid] = A; sAB[16+tid] = bte[tid] - (float)mu * A;
  }
  __syncthreads();

  float lsum = 0.0f;
  for (int t_ = fb + tid; t_ < fe; t_ += 256){
    int s = ei[t_], d = ei[EE+t_];
    const float4* ps = (const float4*)(xc + (size_t)s*CC);
    const float4* pd = (const float4*)(xc + (size_t)d*CC);
    float4 xs0=ps[0], xs1=ps[1], xs2=ps[2], xs3=ps[3];
    float4 xd0=pd[0], xd1=pd[1], xd2=pd[2], xd3=pd[3];
    float fo[16];
#pragma unroll
    for (int c=0;c<16;c++){
      const float4* wr = (const float4*)(sW + c*32);
      float f = sb[c], g_ = sb[c];
      f  = fma4(wr[0],xs0,f);  f  = fma4(wr[1],xs1,f);
      f  = fma4(wr[2],xs2,f);  f  = fma4(wr[3],xs3,f);
      f  = fma4(wr[4],xd0,f);  f  = fma4(wr[5],xd1,f);
      f  = fma4(wr[6],xd2,f);  f  = fma4(wr[7],xd3,f);
      g_ = fma4(wr[0],xd0,g_); g_ = fma4(wr[1],xd1,g_);
      g_ = fma4(wr[2],xd2,g_); g_ = fma4(wr[3],xd3,g_);
      g_ = fma4(wr[4],xs0,g_); g_ = fma4(wr[5],xs1,g_);
      g_ = fma4(wr[6],xs2,g_); g_ = fma4(wr[7],xs3,g_);
      float efv = lrelu(fmaf(sAB[c], f,  sAB[16+c]));
      float ebv = lrelu(fmaf(sAB[c], g_, sAB[16+c]));
      fo[c] = 0.5f*(efv + ebv);
      float dlt = efv - ebv;
      lsum = fmaf(dlt, dlt, lsum);
    }
    float4* po = (float4*)(out + (size_t)t_*CC);
    po[0]=make_float4(fo[0],fo[1],fo[2],fo[3]);
    po[1]=make_float4(fo[4],fo[5],fo[6],fo[7]);
    po[2]=make_float4(fo[8],fo[9],fo[10],fo[11]);
    po[3]=make_float4(fo[12],fo[13],fo[14],fo[15]);
  }
  lsum = waveSum(lsum);
  {
    int lane = tid & 63, w = tid >> 6;
    if (lane == 0) sl[w] = lsum;
    __syncthreads();
    if (tid == 0)
      unsafeAtomicAdd(&lossd[bid & (NB-1)], (double)(sl[0]+sl[1]+sl[2]+sl[3]));
  }
}

// ============= fallback path kernels (round-6, proven) =============
__global__ __launch_bounds__(256) void k_edge_fb(const float* __restrict__ x,
    const int2* __restrict__ sd,
    const float* __restrict__ W, const float* __restrict__ b,
    uint* __restrict__ mh, double* __restrict__ st)
{
  __shared__ float sW[512];
  __shared__ float sb16[16];
  __shared__ float sredS[64], sredQ[64];
  for (int i=threadIdx.x; i<512; i+=256) sW[i] = W[i];
  if (threadIdx.x < 16) sb16[threadIdx.x] = b[threadIdx.x];
  __syncthreads();

  int t = blockIdx.x*256 + threadIdx.x;
  int e0 = 2*t, e1 = 2*t+1;
  bool val = (e1 < EE);
  float acc0[16], acc1[16];
  if (val){
    int2 p0 = sd[e0], p1 = sd[e1];
    float4 xc0[8], xc1[8];
    const float4* p;
    p = (const float4*)(x + (size_t)p0.y*CC); xc0[0]=p[0]; xc0[1]=p[1]; xc0[2]=p[2]; xc0[3]=p[3];
    p = (const float4*)(x + (size_t)p0.x*CC); xc0[4]=p[0]; xc0[5]=p[1]; xc0[6]=p[2]; xc0[7]=p[3];
    p = (const float4*)(x + (size_t)p1.y*CC); xc1[0]=p[0]; xc1[1]=p[1]; xc1[2]=p[2]; xc1[3]=p[3];
    p = (const float4*)(x + (size_t)p1.x*CC); xc1[4]=p[0]; xc1[5]=p[1]; xc1[6]=p[2]; xc1[7]=p[3];
#pragma unroll
    for (int c=0;c<CC;c++){
      const float4* wr = (const float4*)(sW + c*32);
      float a0 = sb16[c], a1 = sb16[c];
#pragma unroll
      for (int q=0;q<8;q++){
        float4 w = wr[q];
        a0 = fma4(w, xc0[q], a0);
        a1 = fma4(w, xc1[q], a1);
      }
      acc0[c]=a0; acc1[c]=a1;
    }
    uint w0[8], w1[8];
#pragma unroll
    for (int q=0;q<8;q++){
      w0[q] = pack_h2(acc0[2*q], acc0[2*q+1]);
      w1[q] = pack_h2(acc1[2*q], acc1[2*q+1]);
    }
    uint4* po0 = (uint4*)(mh + (size_t)e0*8);
    po0[0] = make_uint4(w0[0],w0[1],w0[2],w0[3]);
    po0[1] = make_uint4(w0[4],w0[5],w0[6],w0[7]);
    uint4* po1 = (uint4*)(mh + (size_t)e1*8);
    po1[0] = make_uint4(w1[0],w1[1],w1[2],w1[3]);
    po1[1] = make_uint4(w1[4],w1[5],w1[6],w1[7]);
  } else {
#pragma unroll
    for (int c=0;c<CC;c++){ acc0[c]=0.0f; acc1[c]=0.0f; }
  }

  int lane = threadIdx.x & 63, w = threadIdx.x >> 6;
#pragma unroll
  for (int c=0;c<CC;c++){
    float rs = acc0[c] + acc1[c];
    float rq = acc0[c]*acc0[c] + acc1[c]*acc1[c];
    rs = waveSum(rs); rq = waveSum(rq);
    if (lane == 0){ sredS[w*16+c] = rs; sredQ[w*16+c] = rq; }
  }
  __syncthreads();
  double* stb = st + (size_t)(blockIdx.x & (NB-1))*32;
  if (threadIdx.x < 16){
    int c = threadIdx.x;
    float tot = sredS[c] + sredS[16+c] + sredS[32+c] + sredS[48+c];
    unsafeAtomicAdd(&stb[c], (double)tot);
  } else if (threadIdx.x < 32){
    int c = threadIdx.x - 16;
    float tot = sredQ[c] + sredQ[16+c] + sredQ[32+c] + sredQ[48+c];
    unsafeAtomicAdd(&stb[16+c], (double)tot);
  }
}

__global__ __launch_bounds__(256) void k_node_fb(const uint* __restrict__ mh,
    const int* __restrict__ rp,
    const float* __restrict__ invdeg, const double* __restrict__ st,
    const float* __restrict__ g, const float* __restrict__ bt,
    float* __restrict__ xout)
{
  __shared__ float sA[16], sB[16];
  if (threadIdx.x < 16){
    int c = threadIdx.x;
    double S = 0.0, Q = 0.0;
#pragma unroll
    for (int k=0;k<NB;k++){ S += st[k*32 + c]; Q += st[k*32 + 16 + c]; }
    double mu  = S * (1.0/EE);
    double var = Q * (1.0/EE) - mu*mu;
    float sc = rsqrtf((float)var + 1e-5f);
    float A = sc * g[c];
    sA[c] = A; sB[c] = bt[c] - (float)mu * A;
  }
  __syncthreads();
  int t = blockIdx.x*256 + threadIdx.x;
  int n = t >> 3, cp = t & 7;
  if (n >= NN) return;
  float A0 = sA[2*cp], B0 = sB[2*cp];
  float A1 = sA[2*cp+1], B1 = sB[2*cp+1];
  int beg = rp[n], end = rp[n+1];
  float a0 = 0.0f, a1 = 0.0f;
  for (int i=beg; i<end; i++){
    float2 v = unpack_h2(mh[(size_t)i*8 + cp]);
    a0 += lrelu(fmaf(A0, v.x, B0));
    a1 += lrelu(fmaf(A1, v.y, B1));
  }
  float iv = invdeg[n];
  float2* po = (float2*)(xout + (size_t)n*CC + 2*cp);
  *po = make_float2(a0*iv, a1*iv);
}

__global__ __launch_bounds__(256) void k_final1_fb(const float* __restrict__ x,
    const int* __restrict__ ei, const float* __restrict__ W, const float* __restrict__ b,
    double* __restrict__ st)
{
  __shared__ float sW[512];
  __shared__ float sb16[16];
  __shared__ float sredS[64], sredQ[64];
  for (int i=threadIdx.x; i<512; i+=256) sW[i] = W[i];
  if (threadIdx.x < 16) sb16[threadIdx.x] = b[threadIdx.x];
  __syncthreads();

  int t = blockIdx.x*256 + threadIdx.x;
  bool val = (t < EE);
  float af[16], ab[16];
  if (val){
    int s = ei[t], d = ei[EE+t];
    float4 xs[4], xd[4];
    const float4* p;
    p = (const float4*)(x + (size_t)s*CC); xs[0]=p[0]; xs[1]=p[1]; xs[2]=p[2]; xs[3]=p[3];
    p = (const float4*)(x + (size_t)d*CC); xd[0]=p[0]; xd[1]=p[1]; xd[2]=p[2]; xd[3]=p[3];
#pragma unroll
    for (int c=0;c<CC;c++){
      const float4* wr = (const float4*)(sW + c*32);
      float f = sb16[c], g_ = sb16[c];
#pragma unroll
      for (int q=0;q<4;q++){ float4 w = wr[q];   f = fma4(w, xs[q], f);  g_ = fma4(w, xd[q], g_); }
#pragma unroll
      for (int q=0;q<4;q++){ float4 w = wr[4+q]; f = fma4(w, xd[q], f);  g_ = fma4(w, xs[q], g_); }
      af[c]=f; ab[c]=g_;
    }
  } else {
#pragma unroll
    for (int c=0;c<CC;c++){ af[c]=0.0f; ab[c]=0.0f; }
  }

  int lane = threadIdx.x & 63, w = threadIdx.x >> 6;
#pragma unroll
  for (int c=0;c<CC;c++){
    float rs = af[c] + ab[c];
    float rq = af[c]*af[c] + ab[c]*ab[c];
    rs = waveSum(rs); rq = waveSum(rq);
    if (lane == 0){ sredS[w*16+c] = rs; sredQ[w*16+c] = rq; }
  }
  __syncthreads();
  double* stb = st + (size_t)(blockIdx.x & (NB-1))*32;
  if (threadIdx.x < 16){
    int c = threadIdx.x;
    float tot = sredS[c] + sredS[16+c] + sredS[32+c] + sredS[48+c];
    unsafeAtomicAdd(&stb[c], (double)tot);
  } else if (threadIdx.x < 32){
    int c = threadIdx.x - 16;
    float tot = sredQ[c] + sredQ[16+c] + sredQ[32+c] + sredQ[48+c];
    unsafeAtomicAdd(&stb[16+c], (double)tot);
  }
}

__global__ __launch_bounds__(256) void k_final2_fb(const float* __restrict__ x,
    const int* __restrict__ ei, const float* __restrict__ W, const float* __restrict__ b,
    const double* __restrict__ st, const float* __restrict__ g, const float* __restrict__ bt,
    float* __restrict__ out, double* __restrict__ loss)
{
  __shared__ float sW[512];
  __shared__ float sb16[16];
  __shared__ float sA[16], sB[16];
  __shared__ float sl[4];
  for (int i=threadIdx.x; i<512; i+=256) sW[i] = W[i];
  if (threadIdx.x < 16){
    int c = threadIdx.x;
    sb16[c] = b[c];
    double S = 0.0, Q = 0.0;
#pragma unroll
    for (int k=0;k<NB;k++){ S += st[k*32 + c]; Q += st[k*32 + 16 + c]; }
    double mu  = S * (1.0/(2.0*EE));
    double var = Q * (1.0/(2.0*EE)) - mu*mu;
    float sc = rsqrtf((float)var + 1e-5f);
    float A = sc * g[c];
    sA[c] = A; sB[c] = bt[c] - (float)mu * A;
  }
  __syncthreads();

  int t = blockIdx.x*256 + threadIdx.x;
  bool val = (t < EE);
  float lsum = 0.0f;
  if (val){
    int s = ei[t], d = ei[EE+t];
    float4 xs[4], xd[4];
    const float4* p;
    p = (const float4*)(x + (size_t)s*CC); xs[0]=p[0]; xs[1]=p[1]; xs[2]=p[2]; xs[3]=p[3];
    p = (const float4*)(x + (size_t)d*CC); xd[0]=p[0]; xd[1]=p[1]; xd[2]=p[2]; xd[3]=p[3];
    float fo[16];
#pragma unroll
    for (int c=0;c<CC;c++){
      const float4* wr = (const float4*)(sW + c*32);
      float f = sb16[c], g_ = sb16[c];
#pragma unroll
      for (int q=0;q<4;q++){ float4 w = wr[q];   f = fma4(w, xs[q], f);  g_ = fma4(w, xd[q], g_); }
#pragma unroll
      for (int q=0;q<4;q++){ float4 w = wr[4+q]; f = fma4(w, xd[q], f);  g_ = fma4(w, xs[q], g_); }
      float efv = lrelu(fmaf(sA[c], f,  sB[c]));
      float ebv = lrelu(fmaf(sA[c], g_, sB[c]));
      fo[c] = 0.5f*(efv + ebv);
      float dlt = efv - ebv;
      lsum = fmaf(dlt, dlt, lsum);
    }
    float4* po = (float4*)(out + (size_t)t*CC);
    po[0]=make_float4(fo[0],fo[1],fo[2],fo[3]);
    po[1]=make_float4(fo[4],fo[5],fo[6],fo[7]);
    po[2]=make_float4(fo[8],fo[9],fo[10],fo[11]);
    po[3]=make_float4(fo[12],fo[13],fo[14],fo[15]);
  }
  lsum = waveSum(lsum);
  int lane = threadIdx.x & 63, w = threadIdx.x >> 6;
  if (lane == 0) sl[w] = lsum;
  __syncthreads();
  if (threadIdx.x == 0)
    unsafeAtomicAdd(&loss[blockIdx.x & (NB-1)], (double)(sl[0]+sl[1]+sl[2]+sl[3]));
}

__global__ void k_final3(float* __restrict__ out, const double* __restrict__ loss)
{
  double s = 0.0;
#pragma unroll
  for (int k=0;k<NB;k++) s += loss[k];
  out[(size_t)EE*CC] = (float)(s * (1.0/((double)EE*CC)));
}

// ---------- host ----------
extern "C" void kernel_launch(void* const* d_in, const int* in_sizes, int n_in,
                              void* d_out, int out_size, void* d_ws, size_t ws_size,
                              hipStream_t stream)
{
  (void)in_sizes; (void)n_in; (void)out_size; (void)ws_size;
  const float* ef  = (const float*)d_in[0];
  const int*   ei  = (const int*)d_in[1];
  const float* Wn  = (const float*)d_in[3];
  const float* bn  = (const float*)d_in[4];
  const float* gn  = (const float*)d_in[5];
  const float* btn = (const float*)d_in[6];
  const float* We  = (const float*)d_in[7];
  const float* be  = (const float*)d_in[8];
  const float* ge  = (const float*)d_in[9];
  const float* bte = (const float*)d_in[10];
  float* out = (float*)d_out;
  char* ws = (char*)d_ws;

  size_t off = 0;
  auto alloc = [&](size_t bytes)->size_t{
    size_t r = off; off = (off + bytes + 255) & ~(size_t)255; return r;
  };
  size_t o_xa     = alloc((size_t)NN*CC*4);
  size_t o_xb     = alloc((size_t)NN*CC*4);
  size_t o_mh     = alloc((size_t)EE*8*4);      // fp16 m spill / fallback buffer
  size_t o_cdst   = alloc((size_t)NN*4);
  size_t o_call   = alloc((size_t)NN*4);
  size_t o_rp     = alloc((size_t)(NN+1)*4);
  size_t o_rpall  = alloc((size_t)(NN+1)*4);
  size_t o_cur    = alloc((size_t)NN*4);
  size_t o_curall = alloc((size_t)NN*4);
  size_t o_sd     = alloc((size_t)EE*8);
  size_t o_listall= alloc((size_t)2*EE*4);
  size_t o_bsum   = alloc(512);
  size_t o_bsum2  = alloc(512);
  size_t o_boff   = alloc(512);
  size_t o_boff2  = alloc(512);
  size_t o_stats  = alloc((size_t)(17*NB*32 + NB)*8);
  size_t o_invdeg = alloc((size_t)NN*4);

  float*  x_a     = (float*)(ws + o_xa);
  float*  x_b     = (float*)(ws + o_xb);
  uint*   m_h     = (uint*)(ws + o_mh);
  int*    cdst    = (int*)(ws + o_cdst);
  int*    call_   = (int*)(ws + o_call);
  int*    rp      = (int*)(ws + o_rp);
  int*    rp_all  = (int*)(ws + o_rpall);
  int*    cur     = (int*)(ws + o_cur);
  int*    cur_all = (int*)(ws + o_curall);
  int2*   sd      = (int2*)(ws + o_sd);
  int*    list_all= (int*)(ws + o_listall);
  int*    bsum    = (int*)(ws + o_bsum);
  int*    bsum2   = (int*)(ws + o_bsum2);
  int*    boff    = (int*)(ws + o_boff);
  int*    boff2   = (int*)(ws + o_boff2);
  double* stats   = (double*)(ws + o_stats);
  double* lossd   = stats + (size_t)17*NB*32;
  float*  invdeg  = (float*)(ws + o_invdeg);

  const int GB_E  = (EE + 255)/256;        // 1563
  const int GB_E2 = (EE/2 + 255)/256;      // 782
  const int GB_NC = (NN*CC + 255)/256;     // 6250
  const int GB_N8 = (NN*8 + 255)/256;      // 3125
  const int NSEG  = (NN + 1023)/1024;      // 98

  hipMemsetAsync(cdst, 0, (size_t)NN*4, stream);
  hipMemsetAsync(call_, 0, (size_t)NN*4, stream);
  hipMemsetAsync(stats, 0, (size_t)(17*NB*32 + NB)*8, stream);

  k_count<<<GB_E, 256, 0, stream>>>(ei, cdst, call_);
  k_scan1<<<NSEG, 256, 0, stream>>>(cdst, rp, bsum, call_, rp_all, bsum2, NN);
  k_scan2<<<1, 256, 0, stream>>>(bsum, boff, bsum2, boff2, NSEG);
  k_scan3<<<NSEG, 256, 0, stream>>>(rp, cur, boff, EE, rp_all, cur_all, boff2, 2*EE, NN);
  k_fill<<<GB_E, 256, 0, stream>>>(ei, cur, sd, cur_all, list_all);
  k_gather0<<<GB_NC, 256, 0, stream>>>(ef, rp_all, list_all, rp, x_a, invdeg);

  // ---- cooperative path: size grid by actual occupancy; checked launch ----
  int occ = 0, cus = 0, dev = 0;
  (void)hipGetDevice(&dev);
  (void)hipDeviceGetAttribute(&cus, hipDeviceAttributeMultiprocessorCount, dev);
  (void)hipOccupancyMaxActiveBlocksPerMultiprocessor(&occ, (const void*)k_layers, 256, 0);
  long maxg = (long)occ * (long)(cus > 0 ? cus : 0);
  int grid = (int)(maxg > 1024 ? 1024 : maxg);

  hipError_t cerr = hipErrorUnknown;
  if (grid >= 64){
    void* args[] = {
      (void*)&x_a, (void*)&x_b, (void*)&sd, (void*)&rp, (void*)&invdeg, (void*)&ei,
      (void*)&Wn, (void*)&bn, (void*)&gn, (void*)&btn,
      (void*)&We, (void*)&be, (void*)&ge, (void*)&bte,
      (void*)&stats, (void*)&lossd, (void*)&m_h, (void*)&out
    };
    cerr = hipLaunchCooperativeKernel((void*)k_layers, dim3(grid), dim3(256), args, 0, stream);
  }

  if (cerr != hipSuccess){
    // -------- fallback: proven multi-kernel path --------
    const float* xc = x_a;
    float* xn = x_b;
    for (int l = 0; l < LL; ++l){
      double* st = stats + (size_t)l*NB*32;
      const float* Wl = Wn + (size_t)l*CC*2*CC;
      const float* bl = bn + (size_t)l*CC;
      k_edge_fb<<<GB_E2, 256, 0, stream>>>(xc, sd, Wl, bl, m_h, st);
      k_node_fb<<<GB_N8, 256, 0, stream>>>(m_h, rp, invdeg, st,
                                           gn + (size_t)l*CC, btn + (size_t)l*CC, xn);
      float* tmp = (float*)xc; xc = xn; xn = tmp;
    }
    double* stF = stats + (size_t)LL*NB*32;
    k_final1_fb<<<GB_E, 256, 0, stream>>>(xc, ei, We, be, stF);
    k_final2_fb<<<GB_E, 256, 0, stream>>>(xc, ei, We, be, stF, ge, bte, out, lossd);
  }

  k_final3<<<1, 1, 0, stream>>>(out, lossd);
}